// Round 2
// baseline (130.995 us; speedup 1.0000x reference)
//
#include <hip/hip_runtime.h>

#define H 512
#define W 512
#define HW (H * W)
#define BATCH 32
#define KS 5
#define NBH 8            // batches per block (BATCH/NBH = 4 y-blocks)
#define NSTEP (NBH * KS) // 40 pipelined row-steps per block
#define PD 3             // row-steps of load lookahead

typedef float nf4 __attribute__((ext_vector_type(4)));

// One output row per block. K for that row lives in registers (25 x float4)
// and is reused across NBH batches -> K cache traffic 12.5 B/output and K
// loads vanish from the steady-state loop. f is streamed with a PD-deep
// software pipeline; each f row feeds exactly one tap-row, so no rolling
// window is needed. Top/bottom zero-padding: OOB tap-rows get Kt == 0 (loads
// skipped, block-uniform branch) and a clamped f row address (garbage * 0).
// ~170 VGPR -> 2-3 waves/SIMD; NO LDS, NO BARRIERS.
__global__ __launch_bounds__(128, 2) void op2d_kernel(
    const float* __restrict__ f,   // (B,H,W)
    const float* __restrict__ K,   // (5,5,H,W)
    const float* __restrict__ dt,  // (B,)
    float* __restrict__ out)       // (B,H,W)
{
    const int tid = threadIdx.x;             // 0..127
    const int w0  = tid * 4;                 // 0..508
    const int bx  = blockIdx.x;
    // XCD-contiguous row bands: XCD (bx&7) owns rows [(bx&7)*64, +64).
    // Same-row blocks across y-groups are 512 IDs apart (0 mod 8) -> same
    // XCD -> each K row is HBM-fetched into one XCD's L2, reused 4x.
    const int r   = (bx & 7) * 64 + (bx >> 3);
    const int b0  = blockIdx.y * NBH;

    const bool wl = (w0 >= 4);
    const bool wr = (w0 <= 504);

    // Clamped source-row offsets for the 5 tap-rows (ALU only, no loads).
    int rowoff[KS];
    bool inb[KS];
#pragma unroll
    for (int i = 0; i < KS; ++i) {
        const int gr = r + i - 2;
        inb[i] = (gr >= 0) && (gr < H);
        rowoff[i] = (gr < 0 ? 0 : (gr >= H ? H - 1 : gr)) * W;
    }

    // issue the 3 float4 loads of row-step s (batch s/5, tap-row s%5)
    nf4 rbuf[PD][3];
#define ISSUE(s, d)                                                          \
    {                                                                        \
        const float* fb = f + (size_t)(b0 + (s) / KS) * HW                   \
                            + rowoff[(s) % KS] + w0;                         \
        (d)[0] = wl ? *reinterpret_cast<const nf4*>(fb - 4) : (nf4)0.f;      \
        (d)[1] =      *reinterpret_cast<const nf4*>(fb);                     \
        (d)[2] = wr ? *reinterpret_cast<const nf4*>(fb + 4) : (nf4)0.f;      \
    }

    // f prologue FIRST: queue positions 0..8, drained by the same waitcnt
    // that step 0's Kt row-0 use forces -> earliest-needed data earliest.
#pragma unroll
    for (int s = 0; s < PD; ++s) ISSUE(s, rbuf[s]);

    // ---- K taps for output row r: register-resident for the whole block ----
    // OOB tap-rows are zeroed, not loaded (uniform branch; no WAW drain).
    nf4 Kt[KS * KS];
#pragma unroll
    for (int i = 0; i < KS; ++i) {
        if (inb[i]) {
#pragma unroll
            for (int j = 0; j < KS; ++j)
                Kt[i * KS + j] = *reinterpret_cast<const nf4*>(
                    K + ((size_t)(i * KS + j) * H + r) * W + w0);
        } else {
#pragma unroll
            for (int j = 0; j < KS; ++j) Kt[i * KS + j] = (nf4)0.f;
        }
    }

    float dtb[NBH];
#pragma unroll
    for (int bi = 0; bi < NBH; ++bi) dtb[bi] = dt[b0 + bi];  // uniform -> s_load

    float acc[4] = {0.f, 0.f, 0.f, 0.f};
    float fc[4]  = {0.f, 0.f, 0.f, 0.f};

#pragma unroll
    for (int s = 0; s < NSTEP; ++s) {
        const int bi = s / KS;               // batch index (compile-time)
        const int i  = s % KS;               // tap-row (compile-time)

        // consume current slot (register copies), then refill it PD ahead
        const nf4 ra = rbuf[s % PD][0];
        const nf4 rb = rbuf[s % PD][1];
        const nf4 rc = rbuf[s % PD][2];
        if (s + PD < NSTEP) ISSUE(s + PD, rbuf[(s + PD) % PD]);

        const float buf[12] = { ra.x, ra.y, ra.z, ra.w,
                                rb.x, rb.y, rb.z, rb.w,
                                rc.x, rc.y, rc.z, rc.w };
        if (i == 2) { fc[0] = rb.x; fc[1] = rb.y; fc[2] = rb.z; fc[3] = rb.w; }

        // 20 FMAs, 4 independent acc chains (8cy issue > 4cy latency).
#pragma unroll
        for (int j = 0; j < KS; ++j) {
            const nf4 kv = Kt[i * KS + j];
            acc[0] += kv.x * buf[j + 2];
            acc[1] += kv.y * buf[j + 3];
            acc[2] += kv.z * buf[j + 4];
            acc[3] += kv.w * buf[j + 5];
        }

        if (i == KS - 1) {                   // batch bi complete: store row
            nf4 o;
            o.x = fmaxf(fc[0] + acc[0] * dtb[bi], 0.f);
            o.y = fmaxf(fc[1] + acc[1] * dtb[bi], 0.f);
            o.z = fmaxf(fc[2] + acc[2] * dtb[bi], 0.f);
            o.w = fmaxf(fc[3] + acc[3] * dtb[bi], 0.f);
            __builtin_nontemporal_store(o, reinterpret_cast<nf4*>(
                out + ((size_t)(b0 + bi) * H + r) * W + w0));
            acc[0] = acc[1] = acc[2] = acc[3] = 0.f;
        }
    }
#undef ISSUE
}

extern "C" void kernel_launch(void* const* d_in, const int* in_sizes, int n_in,
                              void* d_out, int out_size, void* d_ws, size_t ws_size,
                              hipStream_t stream) {
    const float* f  = (const float*)d_in[0];   // (32,512,512)
    const float* K  = (const float*)d_in[1];   // (5,5,512,512)
    const float* dt = (const float*)d_in[2];   // (32,)
    float* out = (float*)d_out;

    dim3 block(128);
    dim3 grid(H, BATCH / NBH);   // 512 rows x 4 batch-groups = 2048 blocks
    op2d_kernel<<<grid, block, 0, stream>>>(f, K, dt, out);
}